// Round 9
// baseline (1755.656 us; speedup 1.0000x reference)
//
#include <hip/hip_runtime.h>
#include <math.h>

// Problem constants
#define B_TOT   2048
#define N_IN    1024
#define N_H     1024
#define N_OUT   512
#define N_UPD   1536
#define T_TOT   3072   // MAX_STEPS * N_UPD
#define N_WIN   48     // T_TOT / 64

// ---------------- prep kernels ----------------

// W1T[c*1024 + r] = W1[r*1024 + c]
__global__ void prep_w1t(const float* __restrict__ W1, float* __restrict__ W1T) {
    int idx = blockIdx.x * 256 + threadIdx.x;   // < 1024*1024
    int r = idx & 1023;
    int c = idx >> 10;
    W1T[(size_t)c * 1024 + r] = W1[(size_t)r * 1024 + c];
}

// W2Tf[c*512 + r] = W2[r*1024 + c]
__global__ void prep_w2tf(const float* __restrict__ W2, float* __restrict__ W2Tf) {
    int idx = blockIdx.x * 256 + threadIdx.x;   // < 512*1024
    int r = idx & 511;
    int c = idx >> 9;
    W2Tf[(size_t)c * 512 + r] = W2[(size_t)r * 1024 + c];
}

// WHf[n][lane][j] = W2[(j*64+lane)][n]   (hidden-flip fragment: h2 coupling, 8F/lane)
__global__ void prep_whf(const float* __restrict__ W2, float* __restrict__ WHf) {
    int idx = blockIdx.x * 256 + threadIdx.x;   // < 1024*512
    int n = idx >> 9;
    int r = idx & 511;
    int l = r >> 3, j = r & 7;
    WHf[idx] = W2[(size_t)(j * 64 + l) * 1024 + n];
}

// WOf[nn][lane][j] = W2[nn][j*64+lane]   (output-flip fragment: h1 coupling, 16F/lane)
__global__ void prep_wof(const float* __restrict__ W2, float* __restrict__ WOf) {
    int idx = blockIdx.x * 256 + threadIdx.x;   // < 512*1024
    int nn = idx >> 10;
    int r = idx & 1023;
    int l = r >> 4, j = r & 15;
    WOf[idx] = W2[(size_t)nn * 1024 + j * 64 + l];
}

// WXf[w][j][l]: fp32 coupling of flip at step w*64+j onto decision at step w*64+l.
__global__ void prep_wx(const float* __restrict__ W2, const int* __restrict__ ids,
                        float* __restrict__ WXf) {
    int idx = blockIdx.x * 256 + threadIdx.x;   // < 48*4096
    int w = idx >> 12;
    int j = (idx >> 6) & 63;
    int l = idx & 63;
    int mj = ids[w * 64 + j];
    int nl = ids[w * 64 + l];
    float v = 0.0f;
    if (mj < N_H && nl >= N_H) v = W2[(size_t)(nl - N_H) * 1024 + mj];
    else if (mj >= N_H && nl < N_H) v = W2[(size_t)(mj - N_H) * 1024 + nl];
    WXf[idx] = v;
}

// posA[n] = sweep-1 step of unit n; posB[n] = sweep-2 step - 1536
__global__ void prep_pos(const int* __restrict__ ids, int* __restrict__ posA,
                         int* __restrict__ posB) {
    int t = blockIdx.x * 256 + threadIdx.x;   // < 3072
    int n = ids[t];
    if (t < N_UPD) posA[n] = t; else posB[n] = t - N_UPD;
}

// pos2[t] = posA[ids[1536 + t]]
__global__ void prep_pos2(const int* __restrict__ ids, const int* __restrict__ posA,
                          int* __restrict__ pos2) {
    int t = blockIdx.x * 256 + threadIdx.x;   // < 1536
    pos2[t] = posA[ids[N_UPD + t]];
}

// TH[b][t] = T(t) * logit(u[t][b])  in fp64 (tiled transpose; same formula as before)
__global__ __launch_bounds__(256) void prep_th(const float* __restrict__ u,
                                               double* __restrict__ TH) {
    __shared__ double tile[64][65];
    int bt = blockIdx.x % 48;   // t tile
    int bb = blockIdx.x / 48;   // b tile
    int tx = threadIdx.x & 63;
    int ty0 = threadIdx.x >> 6;
    const double T1c = (double)(float)(2.0 / exp((double)1 / 5.0));
    for (int r = ty0; r < 64; r += 4) {
        int t = bt * 64 + r;
        float uv = u[(size_t)t * 2048 + bb * 64 + tx];
        double T = (t >= N_UPD) ? T1c : 2.0;
        double ud = (double)uv;
        tile[r][tx] = T * (log(ud) - log1p(-ud));
    }
    __syncthreads();
    for (int r = ty0; r < 64; r += 4)
        __builtin_nontemporal_store(tile[tx][r],
            &TH[(size_t)(bb * 64 + r) * 3072 + bt * 64 + tx]);
}

// out[b][0:1024] = x[b][:]
__global__ void copy_x(const float* __restrict__ x, float* __restrict__ out) {
    int idx = blockIdx.x * 256 + threadIdx.x;   // < 2048*256 (float4 units)
    int b = idx >> 8, c = idx & 255;
    ((float4*)(out + (size_t)b * 2560))[c] = ((const float4*)(x + (size_t)b * 1024))[c];
}

// ---------------- init fields (fp64) ----------------
// 8 batch rows per block -> 256 blocks.
__global__ __launch_bounds__(256) void init_fields(
    const float* __restrict__ x, const float* __restrict__ s1i, const float* __restrict__ s2i,
    const float* __restrict__ W1T, const float* __restrict__ W2, const float* __restrict__ W2Tf,
    const float* __restrict__ b1, const float* __restrict__ b2,
    double* __restrict__ h1g, double* __restrict__ h2g)
{
    const int tid = threadIdx.x;
    const int b0 = blockIdx.x * 8;

    __shared__ unsigned char xm[1024];
    __shared__ unsigned char s2msk[512];
    __shared__ unsigned char s1msk[1024];

    for (int i = tid; i < 1024; i += 256) {
        unsigned m = 0;
        #pragma unroll
        for (int b = 0; b < 8; ++b) m |= (x[(size_t)(b0 + b) * 1024 + i] != 0.0f) << b;
        xm[i] = (unsigned char)m;
    }
    for (int j = tid; j < 512; j += 256) {
        unsigned m = 0;
        #pragma unroll
        for (int b = 0; b < 8; ++b) m |= (s2i[(size_t)(b0 + b) * 512 + j] != 0.0f) << b;
        s2msk[j] = (unsigned char)m;
    }
    for (int j = tid; j < 1024; j += 256) {
        unsigned m = 0;
        #pragma unroll
        for (int b = 0; b < 8; ++b) m |= (s1i[(size_t)(b0 + b) * 1024 + j] != 0.0f) << b;
        s1msk[j] = (unsigned char)m;
    }
    __syncthreads();

    double h1r[32];   // h1r[k*8+b], m = k*256 + tid
    #pragma unroll
    for (int k = 0; k < 4; ++k) {
        double bv = (double)b1[k * 256 + tid];
        #pragma unroll
        for (int b = 0; b < 8; ++b) h1r[k * 8 + b] = bv;
    }
    double h2r[16];
    #pragma unroll
    for (int k = 0; k < 2; ++k) {
        double bv = (double)b2[k * 256 + tid];
        #pragma unroll
        for (int b = 0; b < 8; ++b) h2r[k * 8 + b] = bv;
    }

    // part 1: x @ W1^T
    {
        const unsigned* xmu = (const unsigned*)xm;
        unsigned mwn = xmu[0];
        float wc[16];
        #pragma unroll
        for (int s = 0; s < 4; ++s) {
            const float* q = W1T + (size_t)s * 1024 + tid;
            wc[s*4+0] = q[0]; wc[s*4+1] = q[256]; wc[s*4+2] = q[512]; wc[s*4+3] = q[768];
        }
        for (int g = 0; g < 256; ++g) {
            unsigned mg = (unsigned)__builtin_amdgcn_readfirstlane((int)mwn);
            if (g + 1 < 256) mwn = xmu[g + 1];
            float wn[16];
            if (g + 1 < 256) {
                #pragma unroll
                for (int s = 0; s < 4; ++s) {
                    const float* q = W1T + (size_t)(4 * (g + 1) + s) * 1024 + tid;
                    wn[s*4+0] = q[0]; wn[s*4+1] = q[256]; wn[s*4+2] = q[512]; wn[s*4+3] = q[768];
                }
            } else {
                #pragma unroll
                for (int z = 0; z < 16; ++z) wn[z] = wc[z];
            }
            #pragma unroll
            for (int s = 0; s < 4; ++s) {
                unsigned m8 = (mg >> (8 * s)) & 0xFFu;
                if (m8) {
                    double d0 = (double)wc[s*4+0], d1 = (double)wc[s*4+1];
                    double d2 = (double)wc[s*4+2], d3 = (double)wc[s*4+3];
                    #pragma unroll
                    for (int b = 0; b < 8; ++b) if ((m8 >> b) & 1u) {
                        h1r[0 * 8 + b] += d0; h1r[1 * 8 + b] += d1;
                        h1r[2 * 8 + b] += d2; h1r[3 * 8 + b] += d3;
                    }
                }
            }
            #pragma unroll
            for (int z = 0; z < 16; ++z) wc[z] = wn[z];
        }
    }
    // part 2: s2 @ W2
    {
        const unsigned* s2u = (const unsigned*)s2msk;
        unsigned mwn = s2u[0];
        float wc[16];
        #pragma unroll
        for (int s = 0; s < 4; ++s) {
            const float* q = W2 + (size_t)s * 1024 + tid;
            wc[s*4+0] = q[0]; wc[s*4+1] = q[256]; wc[s*4+2] = q[512]; wc[s*4+3] = q[768];
        }
        for (int g = 0; g < 128; ++g) {
            unsigned mg = (unsigned)__builtin_amdgcn_readfirstlane((int)mwn);
            if (g + 1 < 128) mwn = s2u[g + 1];
            float wn[16];
            if (g + 1 < 128) {
                #pragma unroll
                for (int s = 0; s < 4; ++s) {
                    const float* q = W2 + (size_t)(4 * (g + 1) + s) * 1024 + tid;
                    wn[s*4+0] = q[0]; wn[s*4+1] = q[256]; wn[s*4+2] = q[512]; wn[s*4+3] = q[768];
                }
            } else {
                #pragma unroll
                for (int z = 0; z < 16; ++z) wn[z] = wc[z];
            }
            #pragma unroll
            for (int s = 0; s < 4; ++s) {
                unsigned m8 = (mg >> (8 * s)) & 0xFFu;
                if (m8) {
                    double d0 = (double)wc[s*4+0], d1 = (double)wc[s*4+1];
                    double d2 = (double)wc[s*4+2], d3 = (double)wc[s*4+3];
                    #pragma unroll
                    for (int b = 0; b < 8; ++b) if ((m8 >> b) & 1u) {
                        h1r[0 * 8 + b] += d0; h1r[1 * 8 + b] += d1;
                        h1r[2 * 8 + b] += d2; h1r[3 * 8 + b] += d3;
                    }
                }
            }
            #pragma unroll
            for (int z = 0; z < 16; ++z) wc[z] = wn[z];
        }
    }
    // part 3: s1 @ W2^T
    {
        const unsigned* s1u = (const unsigned*)s1msk;
        unsigned mwn = s1u[0];
        float wc[8];
        #pragma unroll
        for (int s = 0; s < 4; ++s) {
            const float* q = W2Tf + (size_t)s * 512 + tid;
            wc[s*2+0] = q[0]; wc[s*2+1] = q[256];
        }
        for (int g = 0; g < 256; ++g) {
            unsigned mg = (unsigned)__builtin_amdgcn_readfirstlane((int)mwn);
            if (g + 1 < 256) mwn = s1u[g + 1];
            float wn[8];
            if (g + 1 < 256) {
                #pragma unroll
                for (int s = 0; s < 4; ++s) {
                    const float* q = W2Tf + (size_t)(4 * (g + 1) + s) * 512 + tid;
                    wn[s*2+0] = q[0]; wn[s*2+1] = q[256];
                }
            } else {
                #pragma unroll
                for (int z = 0; z < 8; ++z) wn[z] = wc[z];
            }
            #pragma unroll
            for (int s = 0; s < 4; ++s) {
                unsigned m8 = (mg >> (8 * s)) & 0xFFu;
                if (m8) {
                    double d0 = (double)wc[s*2+0], d1 = (double)wc[s*2+1];
                    #pragma unroll
                    for (int b = 0; b < 8; ++b) if ((m8 >> b) & 1u) {
                        h2r[0 * 8 + b] += d0; h2r[1 * 8 + b] += d1;
                    }
                }
            }
            #pragma unroll
            for (int z = 0; z < 8; ++z) wc[z] = wn[z];
        }
    }

    #pragma unroll
    for (int k = 0; k < 4; ++k)
        #pragma unroll
        for (int b = 0; b < 8; ++b)
            h1g[(size_t)(b0 + b) * 1024 + k * 256 + tid] = h1r[k * 8 + b];
    #pragma unroll
    for (int k = 0; k < 2; ++k)
        #pragma unroll
        for (int b = 0; b < 8; ++b)
            h2g[(size_t)(b0 + b) * 512 + k * 256 + tid] = h2r[k * 8 + b];
}

// ---------------- Gibbs chain: ONE wave per TWO batch rows ----------------
// Each 64-thread block runs 2 independent chains (rows rA, rB) in one wave:
// decision chains interleave (2x ILP), and apply weight-row loads are shared
// across both rows (union of flips) -- the L2 traffic that bounded rounds 5-8.
// Apply order within a window is type-grouped (hidden pass, then output pass);
// fp64 reorder drift ~1e-13 is far below realized decision margins.

__global__ __launch_bounds__(64, 1) void gibbs(
    const double* __restrict__ TH, const int* __restrict__ ids,
    const float* __restrict__ WHf, const float* __restrict__ WOf,
    const float* __restrict__ WXf,
    const int* __restrict__ pos2, const int* __restrict__ posB,
    const double* __restrict__ h1g, const double* __restrict__ h2g,
    const float* __restrict__ s1i, const float* __restrict__ s2i,
    float* __restrict__ out)
{
    const int lane = threadIdx.x;            // 0..63
    const int rA = blockIdx.x * 2;
    const int rB = rA + 1;

    __shared__ double fldA[1536], fldB[1536];
    __shared__ unsigned long long actA[N_WIN], actB[N_WIN];
    __shared__ unsigned long long sbA[24], sbB[24];

    // fields for both rows: unit m = k*64 + lane
    double a1[16], b1v[16], a2[8], b2v[8];
    #pragma unroll
    for (int k = 0; k < 16; ++k) {
        a1[k]  = h1g[(size_t)rA * 1024 + k * 64 + lane];
        b1v[k] = h1g[(size_t)rB * 1024 + k * 64 + lane];
    }
    #pragma unroll
    for (int k = 0; k < 8; ++k) {
        a2[k]  = h2g[(size_t)rA * 512 + k * 64 + lane];
        b2v[k] = h2g[(size_t)rB * 512 + k * 64 + lane];
    }

    // initial-state bitmasks per row
    #pragma unroll
    for (int k = 0; k < 16; ++k) {
        unsigned long long mA = __ballot(s1i[(size_t)rA * 1024 + k * 64 + lane] != 0.0f);
        unsigned long long mB = __ballot(s1i[(size_t)rB * 1024 + k * 64 + lane] != 0.0f);
        if (lane == 0) { sbA[k] = mA; sbB[k] = mB; }
    }
    #pragma unroll
    for (int k = 0; k < 8; ++k) {
        unsigned long long mA = __ballot(s2i[(size_t)rA * 512 + k * 64 + lane] != 0.0f);
        unsigned long long mB = __ballot(s2i[(size_t)rB * 512 + k * 64 + lane] != 0.0f);
        if (lane == 0) { sbA[16 + k] = mA; sbB[16 + k] = mB; }
    }

    int idw = ids[lane];
    double thA = TH[(size_t)rA * 3072 + lane];
    double thB = TH[(size_t)rB * 3072 + lane];
    int p2c = 0;

    for (int w = 0; w < N_WIN; ++w) {
        const int t0 = w * 64;

        // mirror both rows' fields
        #pragma unroll
        for (int k = 0; k < 16; ++k) {
            fldA[k * 64 + lane] = a1[k];
            fldB[k * 64 + lane] = b1v[k];
        }
        #pragma unroll
        for (int k = 0; k < 8; ++k) {
            fldA[1024 + k * 64 + lane] = a2[k];
            fldB[1024 + k * 64 + lane] = b2v[k];
        }
        __syncthreads();   // single wave: cheap (waitcnt + trivial barrier)
        double gA = fldA[idw];
        double gB = fldB[idw];

        // old state per row
        int oA, oB;
        if (w < 24) {
            unsigned long long svA = sbA[idw >> 6], svB = sbB[idw >> 6];
            oA = (int)((svA >> (idw & 63)) & 1ull);
            oB = (int)((svB >> (idw & 63)) & 1ull);
        } else {
            unsigned long long avA = actA[p2c >> 6], avB = actB[p2c >> 6];
            oA = (int)((avA >> (p2c & 63)) & 1ull);
            oB = (int)((avB >> (p2c & 63)) & 1ull);
        }
        unsigned long long OLDA = __ballot(oA != 0);
        unsigned long long OLDB = __ballot(oB != 0);
        unsigned long long TYPE = __ballot(idw >= N_H);

        // prefetch next window inputs
        int idn = 0; double thAn = 0.0, thBn = 0.0; int p2n = 0;
        if (w + 1 < N_WIN) {
            idn  = ids[t0 + 64 + lane];
            thAn = TH[(size_t)rA * 3072 + t0 + 64 + lane];
            thBn = TH[(size_t)rB * 3072 + t0 + 64 + lane];
            if (w + 1 >= 24) p2n = pos2[(w - 23) * 64 + lane];
        }

        // serial decision loop: both rows interleaved, wx depth-8 stream
        const float* wxp = WXf + ((size_t)w << 12) + lane;
        double wxd[8];
        #pragma unroll
        for (int j = 0; j < 8; ++j) wxd[j] = (double)wxp[(size_t)j * 64];

        unsigned long long AA = 0, AB = 0;
        for (int jo = 0; jo < 64; jo += 8) {
            #pragma unroll
            for (int ji = 0; ji < 8; ++ji) {
                const int j = jo + ji;
                unsigned long long mA = __ballot(gA > thA);
                unsigned long long mB = __ballot(gB > thB);
                int aA = (int)((mA >> j) & 1ull);
                int aB = (int)((mB >> j) & 1ull);
                int oAj = (int)((OLDA >> j) & 1ull);
                int oBj = (int)((OLDB >> j) & 1ull);
                AA |= ((unsigned long long)(unsigned)aA) << j;
                AB |= ((unsigned long long)(unsigned)aB) << j;
                double wv = wxd[ji];
                gA = fma((double)(aA - oAj), wv, gA);
                gB = fma((double)(aB - oBj), wv, gB);
                if (jo + 8 < 64) wxd[ji] = (double)wxp[(size_t)(j + 8) * 64];
            }
        }
        if (lane == 0) { actA[w] = AA; actB[w] = AB; }

        unsigned long long CA = AA ^ OLDA;
        unsigned long long CB = AB ^ OLDB;

        // ---- hidden-flip pass: union of both rows, shared row loads -> h2 ----
        {
            unsigned long long M = (CA | CB) & ~TYPE;
            int j0 = -1, j1 = -1;
            float4 h00, h01, h10, h11;
            if (M) {
                j0 = __builtin_ctzll(M); M &= M - 1;
                int n = __builtin_amdgcn_readlane(idw, j0);
                const float4* p = (const float4*)(WHf + ((size_t)n << 9)) + (lane << 1);
                h00 = p[0]; h01 = p[1];
            }
            if (M) {
                j1 = __builtin_ctzll(M); M &= M - 1;
                int n = __builtin_amdgcn_readlane(idw, j1);
                const float4* p = (const float4*)(WHf + ((size_t)n << 9)) + (lane << 1);
                h10 = p[0]; h11 = p[1];
            }
            while (j0 >= 0) {
                if ((CA >> j0) & 1ull) {
                    double s = ((AA >> j0) & 1ull) ? 1.0 : -1.0;
                    a2[0] = fma(s, (double)h00.x, a2[0]);
                    a2[1] = fma(s, (double)h00.y, a2[1]);
                    a2[2] = fma(s, (double)h00.z, a2[2]);
                    a2[3] = fma(s, (double)h00.w, a2[3]);
                    a2[4] = fma(s, (double)h01.x, a2[4]);
                    a2[5] = fma(s, (double)h01.y, a2[5]);
                    a2[6] = fma(s, (double)h01.z, a2[6]);
                    a2[7] = fma(s, (double)h01.w, a2[7]);
                }
                if ((CB >> j0) & 1ull) {
                    double s = ((AB >> j0) & 1ull) ? 1.0 : -1.0;
                    b2v[0] = fma(s, (double)h00.x, b2v[0]);
                    b2v[1] = fma(s, (double)h00.y, b2v[1]);
                    b2v[2] = fma(s, (double)h00.z, b2v[2]);
                    b2v[3] = fma(s, (double)h00.w, b2v[3]);
                    b2v[4] = fma(s, (double)h01.x, b2v[4]);
                    b2v[5] = fma(s, (double)h01.y, b2v[5]);
                    b2v[6] = fma(s, (double)h01.z, b2v[6]);
                    b2v[7] = fma(s, (double)h01.w, b2v[7]);
                }
                j0 = j1; h00 = h10; h01 = h11;
                j1 = -1;
                if (M) {
                    j1 = __builtin_ctzll(M); M &= M - 1;
                    int n = __builtin_amdgcn_readlane(idw, j1);
                    const float4* p = (const float4*)(WHf + ((size_t)n << 9)) + (lane << 1);
                    h10 = p[0]; h11 = p[1];
                }
            }
        }

        // ---- output-flip pass: union of both rows, shared row loads -> h1 ----
        {
            unsigned long long M = (CA | CB) & TYPE;
            int j0 = -1, j1 = -1;
            float4 r00, r01, r02, r03, r10, r11, r12, r13;
            if (M) {
                j0 = __builtin_ctzll(M); M &= M - 1;
                int n = __builtin_amdgcn_readlane(idw, j0);
                const float4* p = (const float4*)(WOf + ((size_t)(n - N_H) << 10)) + (lane << 2);
                r00 = p[0]; r01 = p[1]; r02 = p[2]; r03 = p[3];
            }
            if (M) {
                j1 = __builtin_ctzll(M); M &= M - 1;
                int n = __builtin_amdgcn_readlane(idw, j1);
                const float4* p = (const float4*)(WOf + ((size_t)(n - N_H) << 10)) + (lane << 2);
                r10 = p[0]; r11 = p[1]; r12 = p[2]; r13 = p[3];
            }
            while (j0 >= 0) {
                if ((CA >> j0) & 1ull) {
                    double s = ((AA >> j0) & 1ull) ? 1.0 : -1.0;
                    a1[0]  = fma(s, (double)r00.x, a1[0]);
                    a1[1]  = fma(s, (double)r00.y, a1[1]);
                    a1[2]  = fma(s, (double)r00.z, a1[2]);
                    a1[3]  = fma(s, (double)r00.w, a1[3]);
                    a1[4]  = fma(s, (double)r01.x, a1[4]);
                    a1[5]  = fma(s, (double)r01.y, a1[5]);
                    a1[6]  = fma(s, (double)r01.z, a1[6]);
                    a1[7]  = fma(s, (double)r01.w, a1[7]);
                    a1[8]  = fma(s, (double)r02.x, a1[8]);
                    a1[9]  = fma(s, (double)r02.y, a1[9]);
                    a1[10] = fma(s, (double)r02.z, a1[10]);
                    a1[11] = fma(s, (double)r02.w, a1[11]);
                    a1[12] = fma(s, (double)r03.x, a1[12]);
                    a1[13] = fma(s, (double)r03.y, a1[13]);
                    a1[14] = fma(s, (double)r03.z, a1[14]);
                    a1[15] = fma(s, (double)r03.w, a1[15]);
                }
                if ((CB >> j0) & 1ull) {
                    double s = ((AB >> j0) & 1ull) ? 1.0 : -1.0;
                    b1v[0]  = fma(s, (double)r00.x, b1v[0]);
                    b1v[1]  = fma(s, (double)r00.y, b1v[1]);
                    b1v[2]  = fma(s, (double)r00.z, b1v[2]);
                    b1v[3]  = fma(s, (double)r00.w, b1v[3]);
                    b1v[4]  = fma(s, (double)r01.x, b1v[4]);
                    b1v[5]  = fma(s, (double)r01.y, b1v[5]);
                    b1v[6]  = fma(s, (double)r01.z, b1v[6]);
                    b1v[7]  = fma(s, (double)r01.w, b1v[7]);
                    b1v[8]  = fma(s, (double)r02.x, b1v[8]);
                    b1v[9]  = fma(s, (double)r02.y, b1v[9]);
                    b1v[10] = fma(s, (double)r02.z, b1v[10]);
                    b1v[11] = fma(s, (double)r02.w, b1v[11]);
                    b1v[12] = fma(s, (double)r03.x, b1v[12]);
                    b1v[13] = fma(s, (double)r03.y, b1v[13]);
                    b1v[14] = fma(s, (double)r03.z, b1v[14]);
                    b1v[15] = fma(s, (double)r03.w, b1v[15]);
                }
                j0 = j1; r00 = r10; r01 = r11; r02 = r12; r03 = r13;
                j1 = -1;
                if (M) {
                    j1 = __builtin_ctzll(M); M &= M - 1;
                    int n = __builtin_amdgcn_readlane(idw, j1);
                    const float4* p = (const float4*)(WOf + ((size_t)(n - N_H) << 10)) + (lane << 2);
                    r10 = p[0]; r11 = p[1]; r12 = p[2]; r13 = p[3];
                }
            }
        }

        idw = idn; thA = thAn; thB = thBn; p2c = p2n;
    }

    __syncthreads();

    // epilogue: final states = sweep-2 decision bits, both rows
    #pragma unroll
    for (int k = 0; k < 16; ++k) {
        int p = posB[k * 64 + lane];
        unsigned long long avA = actA[24 + (p >> 6)];
        unsigned long long avB = actB[24 + (p >> 6)];
        out[(size_t)rA * 2560 + 1024 + k * 64 + lane] = (float)((avA >> (p & 63)) & 1ull);
        out[(size_t)rB * 2560 + 1024 + k * 64 + lane] = (float)((avB >> (p & 63)) & 1ull);
    }
    #pragma unroll
    for (int k = 0; k < 8; ++k) {
        int p = posB[1024 + k * 64 + lane];
        unsigned long long avA = actA[24 + (p >> 6)];
        unsigned long long avB = actB[24 + (p >> 6)];
        out[(size_t)rA * 2560 + 2048 + k * 64 + lane] = (float)((avA >> (p & 63)) & 1ull);
        out[(size_t)rB * 2560 + 2048 + k * 64 + lane] = (float)((avB >> (p & 63)) & 1ull);
    }
}

// ---------------- launch ----------------
extern "C" void kernel_launch(void* const* d_in, const int* in_sizes, int n_in,
                              void* d_out, int out_size, void* d_ws, size_t ws_size,
                              hipStream_t stream) {
    const float* x   = (const float*)d_in[0];
    const float* s1i = (const float*)d_in[1];
    const float* s2i = (const float*)d_in[2];
    const float* W1  = (const float*)d_in[3];
    const float* b1  = (const float*)d_in[4];
    const float* W2  = (const float*)d_in[5];
    const float* b2  = (const float*)d_in[6];
    const float* u   = (const float*)d_in[7];
    const int*   ids = (const int*)d_in[8];
    float* out = (float*)d_out;

    char* ws = (char*)d_ws;
    float*  W1T  = (float*) (ws);                               //  4 MB
    float*  W2Tf = (float*) (ws + ((size_t)4  << 20));          //  2 MB
    float*  WHf  = (float*) (ws + ((size_t)6  << 20));          //  2 MB
    float*  WOf  = (float*) (ws + ((size_t)8  << 20));          //  2 MB
    float*  WXf  = (float*) (ws + ((size_t)10 << 20));          //  768 KB
    int*    posA = (int*)   (ws + ((size_t)11 << 20));          //  6 KB
    int*    posB = (int*)   (ws + ((size_t)11 << 20) + 8192);   //  6 KB
    int*    pos2 = (int*)   (ws + ((size_t)11 << 20) + 16384);  //  6 KB
    double* THd  = (double*)(ws + ((size_t)12 << 20));          // 48 MB
    double* h1g  = (double*)(ws + ((size_t)60 << 20));          // 16 MB
    double* h2g  = (double*)(ws + ((size_t)76 << 20));          //  8 MB (total 84 MB)

    hipLaunchKernelGGL(prep_w1t,  dim3(4096), dim3(256), 0, stream, W1, W1T);
    hipLaunchKernelGGL(prep_w2tf, dim3(2048), dim3(256), 0, stream, W2, W2Tf);
    hipLaunchKernelGGL(prep_whf,  dim3(2048), dim3(256), 0, stream, W2, WHf);
    hipLaunchKernelGGL(prep_wof,  dim3(2048), dim3(256), 0, stream, W2, WOf);
    hipLaunchKernelGGL(prep_wx,   dim3(768),  dim3(256), 0, stream, W2, ids, WXf);
    hipLaunchKernelGGL(prep_pos,  dim3(12),   dim3(256), 0, stream, ids, posA, posB);
    hipLaunchKernelGGL(prep_pos2, dim3(6),    dim3(256), 0, stream, ids, posA, pos2);
    hipLaunchKernelGGL(prep_th,   dim3(1536), dim3(256), 0, stream, u, THd);
    hipLaunchKernelGGL(copy_x,    dim3(2048), dim3(256), 0, stream, x, out);
    hipLaunchKernelGGL(init_fields, dim3(256), dim3(256), 0, stream,
                       x, s1i, s2i, W1T, W2, W2Tf, b1, b2, h1g, h2g);
    hipLaunchKernelGGL(gibbs, dim3(1024), dim3(64), 0, stream,
                       THd, ids, WHf, WOf, WXf, pos2, posB, h1g, h2g, s1i, s2i, out);
}